// Round 4
// baseline (1339.685 us; speedup 1.0000x reference)
//
#include <hip/hip_runtime.h>
#include <hip/hip_bf16.h>
#include <stdint.h>

#define B_SZ 4
#define H_N 8
#define S_LEN 2048
#define D_HEAD 256
#define HD 2048

typedef __attribute__((ext_vector_type(8))) short bf16x8;
typedef __attribute__((ext_vector_type(4))) float f32x4;
typedef __hip_bfloat16 bf16;

__device__ __forceinline__ short f2bf(float f) {
  bf16 h = __float2bfloat16(f);
  return *reinterpret_cast<short*>(&h);
}

// ---------------- f32 -> bf16 convert (weights) ----------------
__global__ __launch_bounds__(256) void cvt_kernel(const float* __restrict__ src,
                                                  bf16* __restrict__ dst, int n) {
  int i = (blockIdx.x * 256 + threadIdx.x) * 8;
  if (i + 7 < n) {
    float4 a = *(const float4*)(src + i);
    float4 b = *(const float4*)(src + i + 4);
    bf16x8 o;
    o[0] = f2bf(a.x); o[1] = f2bf(a.y); o[2] = f2bf(a.z); o[3] = f2bf(a.w);
    o[4] = f2bf(b.x); o[5] = f2bf(b.y); o[6] = f2bf(b.z); o[7] = f2bf(b.w);
    *reinterpret_cast<bf16x8*>(dst + i) = o;
  }
}

// ---------------- projection GEMM: X[8192,256] @ W[2048,256]^T + b ----------------
__global__ __launch_bounds__(256) void proj_gemm(const float* __restrict__ X,
                                                 const bf16* __restrict__ W,
                                                 const float* __restrict__ bias,
                                                 bf16* __restrict__ Out, float scale,
                                                 int vtrans) {
  int tid = threadIdx.x;
  int w = tid >> 6, l = tid & 63;
  int l15 = l & 15, lg = l >> 4;
  int m0 = blockIdx.x * 64 + w * 16;
  int n0 = blockIdx.y * 64;

  f32x4 acc[4];
#pragma unroll
  for (int n = 0; n < 4; ++n) acc[n] = f32x4{0.f, 0.f, 0.f, 0.f};

  const float* xrow = X + (size_t)(m0 + l15) * 256 + lg * 8;
#pragma unroll
  for (int kb = 0; kb < 8; ++kb) {
    float4 xa = *(const float4*)(xrow + kb * 32);
    float4 xb = *(const float4*)(xrow + kb * 32 + 4);
    bf16x8 af;
    af[0] = f2bf(xa.x); af[1] = f2bf(xa.y); af[2] = f2bf(xa.z); af[3] = f2bf(xa.w);
    af[4] = f2bf(xb.x); af[5] = f2bf(xb.y); af[6] = f2bf(xb.z); af[7] = f2bf(xb.w);
#pragma unroll
    for (int n = 0; n < 4; ++n) {
      bf16x8 wf = *(const bf16x8*)(W + (size_t)(n0 + n * 16 + l15) * 256 + kb * 32 + lg * 8);
      acc[n] = __builtin_amdgcn_mfma_f32_16x16x32_bf16(af, wf, acc[n], 0, 0, 0);
    }
  }
#pragma unroll
  for (int n = 0; n < 4; ++n) {
    int e = n0 + n * 16 + l15;
    float bv = bias[e];
#pragma unroll
    for (int r = 0; r < 4; ++r) {
      int m = m0 + lg * 4 + r;
      int b = m >> 11, s = m & 2047;
      int h = s >> 8;
      int sp = ((s & 255) << 3) | (e >> 8);
      int d = e & 255;
      size_t off = vtrans
          ? (((size_t)(b * 8 + h) * D_HEAD) + d) * S_LEN + sp       // [B*H, D, S']
          : (((size_t)(b * 8 + h) * S_LEN) + sp) * D_HEAD + d;      // [B*H, S', D]
      Out[off] = __float2bfloat16((acc[n][r] + bv) * scale);
    }
  }
}

// ---------------- flash attention ----------------
// 1024 blocks; XCD remap keeps each head's K/V L2-resident.
// 4 independent waves x 16 q-rows; KVBLK=32; K/V^T read DIRECT from global
// (L1/L2-hit) -- no K/V LDS, no barriers, no staging registers.
__global__ __launch_bounds__(256, 3) void attn_kernel(const bf16* __restrict__ Qp,
                                                      const bf16* __restrict__ Kp,
                                                      const bf16* __restrict__ Vt,
                                                      bf16* __restrict__ AL) {
  __shared__ __align__(16) bf16 Ps[4][16 * 40];   // per-wave P tile, stride 40

  int tid = threadIdx.x;
  int w = tid >> 6, l = tid & 63;
  int l15 = l & 15, lg = l >> 4;

  // XCD-aware remap: xcd = bid&7 (round-robin dispatch); qt cycles fastest
  int bid = blockIdx.x;
  int xcd = bid & 7, j = bid >> 3;
  int bh = xcd + 8 * (j >> 5);
  int qt = j & 31;

  const bf16* Qb = Qp + (size_t)bh * S_LEN * D_HEAD;
  const bf16* Kb = Kp + (size_t)bh * S_LEN * D_HEAD;
  const bf16* Vb = Vt + (size_t)bh * (size_t)D_HEAD * S_LEN;

  int q0 = qt * 64 + w * 16;

  bf16x8 qf[8];
#pragma unroll
  for (int kb = 0; kb < 8; ++kb)
    qf[kb] = *(const bf16x8*)(Qb + (size_t)(q0 + l15) * D_HEAD + kb * 32 + lg * 8);

  f32x4 acc[16];
#pragma unroll
  for (int n = 0; n < 16; ++n) acc[n] = f32x4{0.f, 0.f, 0.f, 0.f};
  f32x4 acc_l = f32x4{0.f, 0.f, 0.f, 0.f};   // softmax denominator via ones-column MFMA
  float m_r[4] = {-__builtin_inff(), -__builtin_inff(), -__builtin_inff(), -__builtin_inff()};

  bf16x8 ones;
#pragma unroll
  for (int i = 0; i < 8; ++i) ones[i] = (short)0x3F80;

  const float THR = 4.0f;   // defer-max threshold (T13)

  int prd = l15 * 40 + lg * 8;
  const bf16* vbase = Vb + (size_t)l15 * S_LEN + lg * 8;

  for (int kt = 0; kt < 64; ++kt) {
    // ---- QK^T direct from global (L1/L2-hit) ----
    f32x4 sc0 = f32x4{0.f, 0.f, 0.f, 0.f}, sc1 = f32x4{0.f, 0.f, 0.f, 0.f};
    {
      const bf16* k0 = Kb + (size_t)(kt * 32 + l15) * D_HEAD + lg * 8;
      const bf16* k1 = k0 + 16 * D_HEAD;
      __builtin_amdgcn_s_setprio(1);
#pragma unroll
      for (int kb = 0; kb < 8; ++kb) {
        bf16x8 kf0 = *(const bf16x8*)(k0 + kb * 32);
        bf16x8 kf1 = *(const bf16x8*)(k1 + kb * 32);
        sc0 = __builtin_amdgcn_mfma_f32_16x16x32_bf16(qf[kb], kf0, sc0, 0, 0, 0);
        sc1 = __builtin_amdgcn_mfma_f32_16x16x32_bf16(qf[kb], kf1, sc1, 0, 0, 0);
      }
      __builtin_amdgcn_s_setprio(0);
    }

    // ---- online softmax with defer-max ----
    float pm[4];
#pragma unroll
    for (int r = 0; r < 4; ++r) {
      float v = fmaxf(sc0[r], sc1[r]);
      v = fmaxf(v, __shfl_xor(v, 1));
      v = fmaxf(v, __shfl_xor(v, 2));
      v = fmaxf(v, __shfl_xor(v, 4));
      v = fmaxf(v, __shfl_xor(v, 8));
      pm[r] = v;
    }
    bool need = (pm[0] > m_r[0] + THR) || (pm[1] > m_r[1] + THR) ||
                (pm[2] > m_r[2] + THR) || (pm[3] > m_r[3] + THR);
    if (__ballot(need)) {
#pragma unroll
      for (int r = 0; r < 4; ++r) {
        float mn = fmaxf(m_r[r], pm[r]);
        float esc = __expf(m_r[r] - mn);
        m_r[r] = mn;
#pragma unroll
        for (int n = 0; n < 16; ++n) acc[n][r] *= esc;
        acc_l[r] *= esc;
      }
    }
#pragma unroll
    for (int r = 0; r < 4; ++r) {
      float p0 = __expf(sc0[r] - m_r[r]);
      float p1 = __expf(sc1[r] - m_r[r]);
      int qr = lg * 4 + r;
      Ps[w][qr * 40 + l15] = __float2bfloat16(p0);
      Ps[w][qr * 40 + 16 + l15] = __float2bfloat16(p1);
    }

    // ---- PV: A = P (wave-local LDS), B = V^T rows direct from global ----
    bf16x8 pa = *(const bf16x8*)(&Ps[w][prd]);
    const bf16* vrow = vbase + kt * 32;
    __builtin_amdgcn_s_setprio(1);
    acc_l = __builtin_amdgcn_mfma_f32_16x16x32_bf16(pa, ones, acc_l, 0, 0, 0);
#pragma unroll
    for (int n = 0; n < 16; ++n) {
      bf16x8 vbf = *(const bf16x8*)(vrow + (size_t)n * 16 * S_LEN);
      acc[n] = __builtin_amdgcn_mfma_f32_16x16x32_bf16(pa, vbf, acc[n], 0, 0, 0);
    }
    __builtin_amdgcn_s_setprio(0);
  }

  // ---- epilogue: normalize, store to attn_lin[b, s', h*256+d] ----
  int b = bh >> 3, h = bh & 7;
#pragma unroll
  for (int r = 0; r < 4; ++r) {
    float inv = 1.0f / acc_l[r];
    int q = q0 + lg * 4 + r;
    bf16* orow = AL + ((size_t)b * S_LEN + q) * HD + h * D_HEAD;
#pragma unroll
    for (int n = 0; n < 16; ++n)
      orow[n * 16 + l15] = __float2bfloat16(acc[n][r] * inv);
  }
}

// ---------------- output GEMM: AL[8192,2048] @ Wo[256,2048]^T + bo -> f32 ----------------
__global__ __launch_bounds__(256) void out_gemm(const bf16* __restrict__ A,
                                                const bf16* __restrict__ W,
                                                const float* __restrict__ bias,
                                                float* __restrict__ Out) {
  int tid = threadIdx.x;
  int w = tid >> 6, l = tid & 63;
  int l15 = l & 15, lg = l >> 4;
  int m0 = blockIdx.x * 64 + w * 16;
  int n0 = blockIdx.y * 64;
  f32x4 acc[4];
#pragma unroll
  for (int n = 0; n < 4; ++n) acc[n] = f32x4{0.f, 0.f, 0.f, 0.f};
  const bf16* arow = A + (size_t)(m0 + l15) * HD + lg * 8;
#pragma unroll 8
  for (int kb = 0; kb < 64; ++kb) {
    bf16x8 af = *(const bf16x8*)(arow + kb * 32);
#pragma unroll
    for (int n = 0; n < 4; ++n) {
      bf16x8 wf = *(const bf16x8*)(W + (size_t)(n0 + n * 16 + l15) * HD + kb * 32 + lg * 8);
      acc[n] = __builtin_amdgcn_mfma_f32_16x16x32_bf16(af, wf, acc[n], 0, 0, 0);
    }
  }
#pragma unroll
  for (int n = 0; n < 4; ++n) {
    int d = n0 + n * 16 + l15;
    float bv = bias[d];
#pragma unroll
    for (int r = 0; r < 4; ++r)
      Out[(size_t)(m0 + lg * 4 + r) * 256 + d] = acc[n][r] + bv;
  }
}

extern "C" void kernel_launch(void* const* d_in, const int* in_sizes, int n_in,
                              void* d_out, int out_size, void* d_ws, size_t ws_size,
                              hipStream_t stream) {
  (void)in_sizes; (void)n_in; (void)out_size; (void)ws_size;
  const float* query  = (const float*)d_in[0];
  const float* key    = (const float*)d_in[1];
  const float* values = (const float*)d_in[2];
  const float* Wq = (const float*)d_in[3];
  const float* bq = (const float*)d_in[4];
  const float* Wk = (const float*)d_in[5];
  const float* bk = (const float*)d_in[6];
  const float* Wv = (const float*)d_in[7];
  const float* bv = (const float*)d_in[8];
  const float* Wo = (const float*)d_in[9];
  const float* bo = (const float*)d_in[10];
  float* out = (float*)d_out;

  bf16* ws = (bf16*)d_ws;
  const size_t NP = (size_t)B_SZ * H_N * S_LEN * D_HEAD;  // 16,777,216
  const size_t NW = (size_t)HD * D_HEAD;                  // 524,288
  bf16* Qp  = ws;
  bf16* Kp  = Qp + NP;
  bf16* Vtp = Kp + NP;   // V transposed: [B*H, D, S']
  bf16* ALb = Vtp + NP;
  bf16* Wqb = ALb + NP;
  bf16* Wkb = Wqb + NW;
  bf16* Wvb = Wkb + NW;
  bf16* Wob = Wvb + NW;

  cvt_kernel<<<256, 256, 0, stream>>>(Wq, Wqb, (int)NW);
  cvt_kernel<<<256, 256, 0, stream>>>(Wk, Wkb, (int)NW);
  cvt_kernel<<<256, 256, 0, stream>>>(Wv, Wvb, (int)NW);
  cvt_kernel<<<256, 256, 0, stream>>>(Wo, Wob, (int)NW);

  dim3 pg(128, 32);
  proj_gemm<<<pg, 256, 0, stream>>>(query,  Wqb, bq, Qp,  1.0f / 16.0f, 0);  // 1/sqrt(d_k) folded
  proj_gemm<<<pg, 256, 0, stream>>>(key,    Wkb, bk, Kp,  1.0f, 0);
  proj_gemm<<<pg, 256, 0, stream>>>(values, Wvb, bv, Vtp, 1.0f, 1);          // transposed store

  attn_kernel<<<1024, 256, 0, stream>>>(Qp, Kp, Vtp, ALb);

  out_gemm<<<dim3(128, 4), 256, 0, stream>>>(ALb, Wob, bo, out);
}

// Round 5
// 703.198 us; speedup vs baseline: 1.9051x; 1.9051x over previous
//
#include <hip/hip_runtime.h>
#include <hip/hip_bf16.h>
#include <stdint.h>

#define B_SZ 4
#define H_N 8
#define S_LEN 2048
#define D_HEAD 256
#define HD 2048

typedef __attribute__((ext_vector_type(8))) short bf16x8;
typedef __attribute__((ext_vector_type(4))) float f32x4;
typedef __hip_bfloat16 bf16;

typedef __attribute__((address_space(1))) const void glob_cv;
typedef __attribute__((address_space(3))) void lds_v;

__device__ __forceinline__ short f2bf(float f) {
  bf16 h = __float2bfloat16(f);
  return *reinterpret_cast<short*>(&h);
}

// ---------------- f32 -> bf16 convert (weights) ----------------
__global__ __launch_bounds__(256) void cvt_kernel(const float* __restrict__ src,
                                                  bf16* __restrict__ dst, int n) {
  int i = (blockIdx.x * 256 + threadIdx.x) * 8;
  if (i + 7 < n) {
    float4 a = *(const float4*)(src + i);
    float4 b = *(const float4*)(src + i + 4);
    bf16x8 o;
    o[0] = f2bf(a.x); o[1] = f2bf(a.y); o[2] = f2bf(a.z); o[3] = f2bf(a.w);
    o[4] = f2bf(b.x); o[5] = f2bf(b.y); o[6] = f2bf(b.z); o[7] = f2bf(b.w);
    *reinterpret_cast<bf16x8*>(dst + i) = o;
  }
}

// ---------------- projection GEMM: X[8192,256] @ W[2048,256]^T + b ----------------
__global__ __launch_bounds__(256) void proj_gemm(const float* __restrict__ X,
                                                 const bf16* __restrict__ W,
                                                 const float* __restrict__ bias,
                                                 bf16* __restrict__ Out, float scale,
                                                 int vtrans) {
  int tid = threadIdx.x;
  int w = tid >> 6, l = tid & 63;
  int l15 = l & 15, lg = l >> 4;
  int m0 = blockIdx.x * 64 + w * 16;
  int n0 = blockIdx.y * 64;

  f32x4 acc[4];
#pragma unroll
  for (int n = 0; n < 4; ++n) acc[n] = f32x4{0.f, 0.f, 0.f, 0.f};

  const float* xrow = X + (size_t)(m0 + l15) * 256 + lg * 8;
#pragma unroll
  for (int kb = 0; kb < 8; ++kb) {
    float4 xa = *(const float4*)(xrow + kb * 32);
    float4 xb = *(const float4*)(xrow + kb * 32 + 4);
    bf16x8 af;
    af[0] = f2bf(xa.x); af[1] = f2bf(xa.y); af[2] = f2bf(xa.z); af[3] = f2bf(xa.w);
    af[4] = f2bf(xb.x); af[5] = f2bf(xb.y); af[6] = f2bf(xb.z); af[7] = f2bf(xb.w);
#pragma unroll
    for (int n = 0; n < 4; ++n) {
      bf16x8 wf = *(const bf16x8*)(W + (size_t)(n0 + n * 16 + l15) * 256 + kb * 32 + lg * 8);
      acc[n] = __builtin_amdgcn_mfma_f32_16x16x32_bf16(af, wf, acc[n], 0, 0, 0);
    }
  }
#pragma unroll
  for (int n = 0; n < 4; ++n) {
    int e = n0 + n * 16 + l15;
    float bv = bias[e];
#pragma unroll
    for (int r = 0; r < 4; ++r) {
      int m = m0 + lg * 4 + r;
      int b = m >> 11, s = m & 2047;
      int h = s >> 8;
      int sp = ((s & 255) << 3) | (e >> 8);
      int d = e & 255;
      size_t off = vtrans
          ? (((size_t)(b * 8 + h) * D_HEAD) + d) * S_LEN + sp       // [B*H, D, S']
          : (((size_t)(b * 8 + h) * S_LEN) + sp) * D_HEAD + d;      // [B*H, S', D]
      Out[off] = __float2bfloat16((acc[n][r] + bv) * scale);
    }
  }
}

// ---------------- flash attention ----------------
// 1024 blocks (XCD remap); 4 waves x 16 q-rows; KVBLK=32.
// K/V tile staged via global_load_lds (no staging VGPRs) into conflict-free
// chunk-major LDS layouts; single-buffered, 2 raw barriers/iter; 4 blocks/CU.
//   K LDS: unit u = cd*32 + kv   (cd = d-16B-chunk 0..31, kv 0..31)   16 KB
//   V LDS: unit u = kvc*256 + d  (kvc = kv-16B-chunk 0..3, d 0..255)  16 KB
__global__ __launch_bounds__(256, 4) void attn_kernel(const bf16* __restrict__ Qp,
                                                      const bf16* __restrict__ Kp,
                                                      const bf16* __restrict__ Vt,
                                                      bf16* __restrict__ AL) {
  __shared__ __align__(16) bf16 KVs[16384];        // 32 KB: K [0,8192), V [8192,16384)
  __shared__ __align__(16) bf16 Ps[4][16 * 40];    // per-wave P tile, 5 KB

  int tid = threadIdx.x;
  int w = tid >> 6, l = tid & 63;
  int l15 = l & 15, lg = l >> 4;
  int l31 = l & 31, hl = l >> 5;

  // XCD-aware remap: xcd = bid&7; qt cycles fastest within a head
  int bid = blockIdx.x;
  int xcd = bid & 7, j = bid >> 3;
  int bh = xcd + 8 * (j >> 5);
  int qt = j & 31;

  const bf16* Qb = Qp + (size_t)bh * S_LEN * D_HEAD;
  const bf16* Kb = Kp + (size_t)bh * S_LEN * D_HEAD;
  const bf16* Vb = Vt + (size_t)bh * (size_t)D_HEAD * S_LEN;

  int q0 = qt * 64 + w * 16;

  bf16x8 qf[8];
#pragma unroll
  for (int kb = 0; kb < 8; ++kb)
    qf[kb] = *(const bf16x8*)(Qb + (size_t)(q0 + l15) * D_HEAD + kb * 32 + lg * 8);

  f32x4 acc[16];
#pragma unroll
  for (int n = 0; n < 16; ++n) acc[n] = f32x4{0.f, 0.f, 0.f, 0.f};
  f32x4 acc_l = f32x4{0.f, 0.f, 0.f, 0.f};   // softmax denom via ones-column MFMA
  float m_r[4] = {-__builtin_inff(), -__builtin_inff(), -__builtin_inff(), -__builtin_inff()};

  bf16x8 ones;
#pragma unroll
  for (int i = 0; i < 8; ++i) ones[i] = (short)0x3F80;

  const float THR = 4.0f;   // defer-max threshold (T13)

  // per-lane DMA source pointers (advanced per iter)
  // waves 0,1 stage K: src = Kb + kv(l31)*512B + (cd = w*16 + i*2 + hl)*16B
  // waves 2,3 stage V: src = Vb + d(lane + (i&3)*64)*4096B + kvc((w-2)*2 + i>>2)*16B
  const char* pK = (const char*)Kb + (size_t)l31 * 512 + (size_t)(w * 256 + hl * 16);
  const char* pV = (const char*)Vb + (size_t)l * 4096 + (size_t)((w - 2) * 32);
  char* ldsK = (char*)&KVs[0] + w * 8192;             // waves 0,1
  char* ldsV = (char*)&KVs[0] + 16384 + (w - 2) * 8192;  // waves 2,3

  int krd = lg * 256 + l15 * 8;            // K frag base (elems)
  int vrd = 8192 + lg * 2048 + l15 * 8;    // V frag base (elems)
  int prd = l15 * 40 + lg * 8;

  for (int kt = 0; kt < 64; ++kt) {
    __builtin_amdgcn_s_barrier();          // tile kt-1 fully consumed by all waves
    if (w < 2) {
#pragma unroll
      for (int i = 0; i < 8; ++i)
        __builtin_amdgcn_global_load_lds((glob_cv*)(pK + i * 32),
                                         (lds_v*)(ldsK + i * 1024), 16, 0, 0);
      pK += 32 * 512;
    } else {
#pragma unroll
      for (int i = 0; i < 8; ++i)
        __builtin_amdgcn_global_load_lds((glob_cv*)(pV + (i & 3) * 262144 + (i >> 2) * 16),
                                         (lds_v*)(ldsV + i * 1024), 16, 0, 0);
      pV += 64;
    }
    asm volatile("s_waitcnt vmcnt(0)" ::: "memory");
    __builtin_amdgcn_s_barrier();          // tile kt staged
    __builtin_amdgcn_sched_barrier(0);

    // ---- QK^T from LDS ----
    f32x4 sc0 = f32x4{0.f, 0.f, 0.f, 0.f}, sc1 = f32x4{0.f, 0.f, 0.f, 0.f};
    __builtin_amdgcn_s_setprio(1);
#pragma unroll
    for (int kb = 0; kb < 8; ++kb) {
      bf16x8 kf0 = *(const bf16x8*)(&KVs[krd + kb * 1024]);
      bf16x8 kf1 = *(const bf16x8*)(&KVs[krd + kb * 1024 + 128]);
      sc0 = __builtin_amdgcn_mfma_f32_16x16x32_bf16(qf[kb], kf0, sc0, 0, 0, 0);
      sc1 = __builtin_amdgcn_mfma_f32_16x16x32_bf16(qf[kb], kf1, sc1, 0, 0, 0);
    }
    __builtin_amdgcn_s_setprio(0);

    // ---- online softmax with defer-max ----
    float pm[4];
#pragma unroll
    for (int r = 0; r < 4; ++r) {
      float v = fmaxf(sc0[r], sc1[r]);
      v = fmaxf(v, __shfl_xor(v, 1));
      v = fmaxf(v, __shfl_xor(v, 2));
      v = fmaxf(v, __shfl_xor(v, 4));
      v = fmaxf(v, __shfl_xor(v, 8));
      pm[r] = v;
    }
    bool need = (pm[0] > m_r[0] + THR) || (pm[1] > m_r[1] + THR) ||
                (pm[2] > m_r[2] + THR) || (pm[3] > m_r[3] + THR);
    if (__ballot(need)) {
#pragma unroll
      for (int r = 0; r < 4; ++r) {
        float mn = fmaxf(m_r[r], pm[r]);
        float esc = __expf(m_r[r] - mn);
        m_r[r] = mn;
#pragma unroll
        for (int n = 0; n < 16; ++n) acc[n][r] *= esc;
        acc_l[r] *= esc;
      }
    }
#pragma unroll
    for (int r = 0; r < 4; ++r) {
      float p0 = __expf(sc0[r] - m_r[r]);
      float p1 = __expf(sc1[r] - m_r[r]);
      int qr = lg * 4 + r;
      Ps[w][qr * 40 + l15] = __float2bfloat16(p0);
      Ps[w][qr * 40 + 16 + l15] = __float2bfloat16(p1);
    }

    // ---- PV from LDS (+ ones-column for denominator) ----
    bf16x8 pa = *(const bf16x8*)(&Ps[w][prd]);
    __builtin_amdgcn_s_setprio(1);
    acc_l = __builtin_amdgcn_mfma_f32_16x16x32_bf16(pa, ones, acc_l, 0, 0, 0);
#pragma unroll
    for (int n = 0; n < 16; ++n) {
      bf16x8 vbf = *(const bf16x8*)(&KVs[vrd + n * 128]);
      acc[n] = __builtin_amdgcn_mfma_f32_16x16x32_bf16(pa, vbf, acc[n], 0, 0, 0);
    }
    __builtin_amdgcn_s_setprio(0);
  }

  // ---- epilogue: normalize, store to attn_lin[b, s', h*256+d] ----
  int b = bh >> 3, h = bh & 7;
#pragma unroll
  for (int r = 0; r < 4; ++r) {
    float inv = 1.0f / acc_l[r];
    int q = q0 + lg * 4 + r;
    bf16* orow = AL + ((size_t)b * S_LEN + q) * HD + h * D_HEAD;
#pragma unroll
    for (int n = 0; n < 16; ++n)
      orow[n * 16 + l15] = __float2bfloat16(acc[n][r] * inv);
  }
}

// ---------------- output GEMM: AL[8192,2048] @ Wo[256,2048]^T + bo -> f32 ----------------
__global__ __launch_bounds__(256) void out_gemm(const bf16* __restrict__ A,
                                                const bf16* __restrict__ W,
                                                const float* __restrict__ bias,
                                                float* __restrict__ Out) {
  int tid = threadIdx.x;
  int w = tid >> 6, l = tid & 63;
  int l15 = l & 15, lg = l >> 4;
  int m0 = blockIdx.x * 64 + w * 16;
  int n0 = blockIdx.y * 64;
  f32x4 acc[4];
#pragma unroll
  for (int n = 0; n < 4; ++n) acc[n] = f32x4{0.f, 0.f, 0.f, 0.f};
  const bf16* arow = A + (size_t)(m0 + l15) * HD + lg * 8;
#pragma unroll 8
  for (int kb = 0; kb < 64; ++kb) {
    bf16x8 af = *(const bf16x8*)(arow + kb * 32);
#pragma unroll
    for (int n = 0; n < 4; ++n) {
      bf16x8 wf = *(const bf16x8*)(W + (size_t)(n0 + n * 16 + l15) * HD + kb * 32 + lg * 8);
      acc[n] = __builtin_amdgcn_mfma_f32_16x16x32_bf16(af, wf, acc[n], 0, 0, 0);
    }
  }
#pragma unroll
  for (int n = 0; n < 4; ++n) {
    int d = n0 + n * 16 + l15;
    float bv = bias[d];
#pragma unroll
    for (int r = 0; r < 4; ++r)
      Out[(size_t)(m0 + lg * 4 + r) * 256 + d] = acc[n][r] + bv;
  }
}

extern "C" void kernel_launch(void* const* d_in, const int* in_sizes, int n_in,
                              void* d_out, int out_size, void* d_ws, size_t ws_size,
                              hipStream_t stream) {
  (void)in_sizes; (void)n_in; (void)out_size; (void)ws_size;
  const float* query  = (const float*)d_in[0];
  const float* key    = (const float*)d_in[1];
  const float* values = (const float*)d_in[2];
  const float* Wq = (const float*)d_in[3];
  const float* bq = (const float*)d_in[4];
  const float* Wk = (const float*)d_in[5];
  const float* bk = (const float*)d_in[6];
  const float* Wv = (const float*)d_in[7];
  const float* bv = (const float*)d_in[8];
  const float* Wo = (const float*)d_in[9];
  const float* bo = (const float*)d_in[10];
  float* out = (float*)d_out;

  bf16* ws = (bf16*)d_ws;
  const size_t NP = (size_t)B_SZ * H_N * S_LEN * D_HEAD;  // 16,777,216
  const size_t NW = (size_t)HD * D_HEAD;                  // 524,288
  bf16* Qp  = ws;
  bf16* Kp  = Qp + NP;
  bf16* Vtp = Kp + NP;   // V transposed: [B*H, D, S']
  bf16* ALb = Vtp + NP;
  bf16* Wqb = ALb + NP;
  bf16* Wkb = Wqb + NW;
  bf16* Wvb = Wkb + NW;
  bf16* Wob = Wvb + NW;

  cvt_kernel<<<256, 256, 0, stream>>>(Wq, Wqb, (int)NW);
  cvt_kernel<<<256, 256, 0, stream>>>(Wk, Wkb, (int)NW);
  cvt_kernel<<<256, 256, 0, stream>>>(Wv, Wvb, (int)NW);
  cvt_kernel<<<256, 256, 0, stream>>>(Wo, Wob, (int)NW);

  dim3 pg(128, 32);
  proj_gemm<<<pg, 256, 0, stream>>>(query,  Wqb, bq, Qp,  1.0f / 16.0f, 0);  // 1/sqrt(d_k) folded
  proj_gemm<<<pg, 256, 0, stream>>>(key,    Wkb, bk, Kp,  1.0f, 0);
  proj_gemm<<<pg, 256, 0, stream>>>(values, Wvb, bv, Vtp, 1.0f, 1);          // transposed store

  attn_kernel<<<1024, 256, 0, stream>>>(Qp, Kp, Vtp, ALb);

  out_gemm<<<dim3(128, 4), 256, 0, stream>>>(ALb, Wob, bo, out);
}